// Round 4
// baseline (23950.099 us; speedup 1.0000x reference)
//
#include <hip/hip_runtime.h>

typedef __bf16 bf16;
typedef bf16 bf16x8 __attribute__((ext_vector_type(8)));
typedef bf16 bf16x4 __attribute__((ext_vector_type(4)));
typedef float f32x4 __attribute__((ext_vector_type(4)));

#define MFMA16(a,b,c) __builtin_amdgcn_mfma_f32_16x16x32_bf16((a),(b),(c),0,0,0)

#define B_N 256
#define T_N 512
#define H_N 768
#define WROW 776      // 768 + 8 pad: 16B-aligned rows, bank-staggered
#define WIHROW 40     // 32 + 8 pad

// ---- device-global scratch (BSS): independent of ws_size ----
__device__ float    g_ctrl[B_N * T_N];          // 512 KB
__device__ bf16     g_hbuf[2 * B_N * H_N];      // 768 KB (bf16 h exchange)
__device__ unsigned g_cnt[256];                 // 8 groups x 32 (128B stride)

__device__ __forceinline__ float sigmoidf_(float x){ return 1.f/(1.f+__expf(-x)); }
__device__ __forceinline__ float tanhf_(float x){
  float e = __expf(-2.f*fabsf(x));
  float t = (1.f-e)/(1.f+e);
  return copysignf(t, x);
}
__device__ __forceinline__ float softplusf_(float x){
  return x > 20.f ? x : log1pf(__expf(x));
}

__global__ void k_zero() {
  if (threadIdx.x < 256) g_cnt[threadIdx.x] = 0u;
}

// ---------------- kernel A: causal encoder Z + ctrl term ----------------
// Z (f32) goes into the outw region of d_out (scratch until the GRU epilogue
// overwrites it with w_pos at step t, after all reads of step t are done).
__global__ __launch_bounds__(256) void k_encode(
    const float* __restrict__ Xm, const float* __restrict__ Xc,
    const float* __restrict__ Aw,
    const float* __restrict__ ew1, const float* __restrict__ eb1,
    const float* __restrict__ ew2, const float* __restrict__ eb2,
    const float* __restrict__ nw,  const float* __restrict__ nb,
    const float* __restrict__ cw,  const float* __restrict__ cb,
    float* __restrict__ Zout)
{
  __shared__ float sA[16][16], sE1[16][32], sE2[16][16], sNW[16][32];
  __shared__ float sEB1[16], sEB2[16], sNB[16];
  __shared__ float sCW[768][16];
  __shared__ float sCB[768];
  const int tid = threadIdx.x;
  for (int i = tid; i < 256; i += 256) sA[i>>4][i&15] = Aw[i];
  for (int i = tid; i < 512; i += 256) sE1[i>>5][i&31] = ew1[i];
  for (int i = tid; i < 256; i += 256) sE2[i>>4][i&15] = ew2[i];
  for (int i = tid; i < 512; i += 256) sNW[i>>5][i&31] = nw[i];
  if (tid < 16) { sEB1[tid]=eb1[tid]; sEB2[tid]=eb2[tid]; sNB[tid]=nb[tid]; }
  for (int i = tid; i < 768*16; i += 256) sCW[i>>4][i&15] = cw[i];
  for (int i = tid; i < 768; i += 256) sCB[i] = cb[i];
  __syncthreads();
  const int idx = blockIdx.x*256 + tid;           // flat (b*T + t)
  const float* xmp = Xm + (size_t)idx*16;
  const float* xcp = Xc + (size_t)idx*16;
  float xm[16], xc[16];
  #pragma unroll
  for (int j=0;j<4;j++){
    *(f32x4*)&xm[j*4] = *(const f32x4*)(xmp + j*4);
    *(f32x4*)&xc[j*4] = *(const f32x4*)(xcp + j*4);
  }
  float snd[16], rcv[16];
  #pragma unroll
  for (int i=0;i<16;i++){
    float s=0.f, r=0.f;
    #pragma unroll
    for (int j=0;j<16;j++){ s += xm[j]*sA[i][j]; r += xm[j]*sA[j][i]; }
    snd[i]=s; rcv[i]=r;
  }
  float he[16];
  #pragma unroll
  for (int i=0;i<16;i++){
    float a = sEB1[i];
    #pragma unroll
    for (int k=0;k<16;k++) a += snd[k]*sE1[i][k];
    #pragma unroll
    for (int k=0;k<16;k++) a += rcv[k]*sE1[i][16+k];
    he[i] = fmaxf(a, 0.f);
  }
  float he2[16];
  #pragma unroll
  for (int i=0;i<16;i++){
    float a = sEB2[i];
    #pragma unroll
    for (int k=0;k<16;k++) a += he[k]*sE2[i][k];
    he2[i] = fmaxf(a, 0.f);
  }
  float* zp = Zout + (size_t)idx*16;
  #pragma unroll
  for (int m=0;m<16;m++){
    float a = sNB[m];
    #pragma unroll
    for (int k=0;k<16;k++) a += xm[k]*sNW[m][k];
    #pragma unroll
    for (int k=0;k<16;k++) a += he2[k]*sNW[m][16+k];
    zp[m] = fmaxf(a, 0.f);
  }
  float cs = 0.f;
  for (int i=0;i<768;i++){
    float a = sCB[i];
    #pragma unroll
    for (int k=0;k<16;k++) a += xc[k]*sCW[i][k];
    cs += fmaxf(a, 0.f);
  }
  g_ctrl[idx] = cs * 0.3f;
}

// ---------------- kernel B: adstock scan + hill + gru-input ----------------
// Reads Z (f32) in-place from Zio (= outw region), overwrites with hill+Z.
// Writes hill (f32) into hill_out (= outc region).
__global__ __launch_bounds__(64) void k_adstock(
    const float* __restrict__ Xm, const float* __restrict__ alpha,
    const float* __restrict__ hill_a, const float* __restrict__ hill_g,
    float* __restrict__ Zio, float* __restrict__ hill_out)
{
  const int gid = blockIdx.x*64 + threadIdx.x;   // (b, m)
  const int b = gid >> 4, m = gid & 15;
  float a  = fminf(fmaxf(alpha[m],  0.f),  1.f);
  float ha = fminf(fmaxf(hill_a[m], 0.1f), 3.f);
  float hg = fminf(fmaxf(hill_g[m], 0.1f), 2.f);
  float gpow = __powf(hg, ha);
  const float* xp = Xm + (size_t)b*T_N*16 + m;
  float prev = 0.f, cmax = 0.f;
  for (int t=0;t<T_N;t++){ float x = xp[(size_t)t*16]; prev = x + a*prev; cmax = fmaxf(cmax, prev); }
  cmax = fmaxf(cmax, 1e-6f);
  float inv = 1.f/cmax;
  prev = 0.f;
  float* zp  = Zio      + (size_t)b*T_N*16 + m;
  float* hp  = hill_out + (size_t)b*T_N*16 + m;
  for (int t=0;t<T_N;t++){
    float x = xp[(size_t)t*16];
    prev = x + a*prev;
    float xn  = fmaxf(prev*inv, 0.f);
    float num = __powf(xn, ha);
    float h   = num / (num + gpow + 1e-8f);
    float z   = zp[(size_t)t*16];
    hp[(size_t)t*16] = h;
    zp[(size_t)t*16] = h + z;
  }
}

// ---------------- kernel C: persistent GRU + fused heads ----------------
// 8 groups (32 batches each) x 32 blocks. Block p owns h-dims [p*24, p*24+24):
// 72 W_hh rows bf16 LDS-resident; per-step group h-exchange (bf16) via
// double-buffered global buffer + device-scope arrival counter. The owning
// block keeps its h slice in f32 (LDS) so the z*h feedback path stays f32.
__device__ __forceinline__ void grp_bar(unsigned* cptr, unsigned target) {
  __threadfence();
  __syncthreads();
  if (threadIdx.x == 0) {
    __hip_atomic_fetch_add(cptr, 1u, __ATOMIC_RELEASE, __HIP_MEMORY_SCOPE_AGENT);
    while (__hip_atomic_load(cptr, __ATOMIC_ACQUIRE, __HIP_MEMORY_SCOPE_AGENT) < target)
      __builtin_amdgcn_s_sleep(1);
  }
  __syncthreads();
  __threadfence();
}

__global__ __launch_bounds__(256, 1) void k_gru(
    const float* __restrict__ Xc,
    const float* __restrict__ Wih, const float* __restrict__ Whh,
    const float* __restrict__ bih, const float* __restrict__ bhh,
    const float* __restrict__ wraww, const float* __restrict__ wrawb,
    const float* __restrict__ regemb, const float* __restrict__ bias,
    const float* __restrict__ h0,
    float* __restrict__ hillZ,       // = outw region (read until step t, then w_pos)
    float* __restrict__ hill,        // = outc region (read hill, overwrite contrib)
    float* __restrict__ outy)
{
  __shared__ __align__(16) bf16 sW[72*WROW];      // 111,744 B
  __shared__ __align__(16) bf16 sWih[72*WIHROW];  //   5,760 B
  __shared__ float sGH[32][84];                   //  10,752 B (gh; r/z merged with gi)
  __shared__ float sGIN[32][36];                  //   4,608 B (gi, n-gate only)
  __shared__ float sHm[32][24];                   //   3,072 B (f32 master h slice)
  __shared__ float sBih[72], sBhh[72];
  __shared__ float sHead[16], sWp0[16], sHill0[16];
  __shared__ float sScal[2];

  const int g = blockIdx.x & 7, p = blockIdx.x >> 3;  // group (XCD-aligned), rank
  const int j0 = p*24;
  const int tid = threadIdx.x;
  const int wave = tid >> 6, lane = tid & 63;
  const int quad = lane >> 4, l16 = lane & 15;

  // stage W_hh slice (f32 -> bf16), rows {gate*768 + j0 + j}
  for (int c = tid; c < 72*192; c += 256) {
    int rl = c / 192, off = (c - rl*192)*4;
    int grow = (rl/24)*768 + j0 + (rl%24);
    f32x4 w = *(const f32x4*)&Whh[(size_t)grow*768 + off];
    bf16x4 v; v[0]=(bf16)w[0]; v[1]=(bf16)w[1]; v[2]=(bf16)w[2]; v[3]=(bf16)w[3];
    *(bf16x4*)&sW[rl*WROW + off] = v;
  }
  for (int c = tid; c < 72*8; c += 256) {
    int rl = c >> 3, off = (c & 7)*4;
    int grow = (rl/24)*768 + j0 + (rl%24);
    f32x4 w = *(const f32x4*)&Wih[(size_t)grow*32 + off];
    bf16x4 v; v[0]=(bf16)w[0]; v[1]=(bf16)w[1]; v[2]=(bf16)w[2]; v[3]=(bf16)w[3];
    *(bf16x4*)&sWih[rl*WIHROW + off] = v;
  }
  if (tid < 72) {
    int grow = (tid/24)*768 + j0 + (tid%24);
    sBih[tid] = bih[grow];
    sBhh[tid] = bhh[grow];
  }
  if (wave == 0) {
    float s = 0.f;
    for (int k = lane; k < 768; k += 64) s += regemb[k];  // reg_emb[0]
    #pragma unroll
    for (int off = 32; off; off >>= 1) s += __shfl_xor(s, off, 64);
    if (lane == 0) { sScal[0] = 0.3f*s; sScal[1] = bias[0]; }
  }
  // init h (parity 0): f32 master + bf16 exchange copy
  for (int i = tid; i < 32*24; i += 256) {
    int b = i/24, j = i - b*24;
    float hv = h0[j0+j];
    sHm[b][j] = hv;
    g_hbuf[(size_t)(g*32+b)*H_N + j0 + j] = (bf16)hv;
  }
  unsigned* cptr = g_cnt + g*32;  // 128B apart per group
  unsigned nbar = 1;
  grp_bar(cptr, nbar*32); nbar++;

  const int mi = wave >> 1;                 // M-tile (batch halves)
  const bool lowN = !(wave & 1);            // n-tiles {0,1,2} vs {3,4}
  const int batch_l = l16 + mi*16;
  const int gb = g*32 + batch_l;
  const int bq = g*32 + p;                  // batch this block heads
  const float regt = sScal[0], bias0 = sScal[1];
  const int m16 = tid >> 4, s16 = tid & 15;
  const int r0 = lowN ? l16        : 48 + l16;
  const int r1 = lowN ? 16 + l16   : min(64 + l16, 71);  // clamp dead cols 72..79
  const int r2 = 32 + l16;                  // lowN only

  int par = 0;
  for (int t = 0; t < T_N; t++) {
    f32x4 a0 = {0.f,0.f,0.f,0.f}, a1 = a0, a2 = a0, gi0 = a0, gi1 = a0;
    // gi = x @ W_ih^T  (x = [hill+Z | Xc], f32 -> bf16 in-register)
    {
      const float* hz = hillZ + ((size_t)gb*T_N + t)*16;
      const float* xr = Xc    + ((size_t)gb*T_N + t)*16;
      const float* src = (quad < 2) ? (hz + quad*8) : (xr + (quad-2)*8);
      f32x4 f0 = *(const f32x4*)src;
      f32x4 f1 = *(const f32x4*)(src + 4);
      bf16x8 ax;
      ax[0]=(bf16)f0[0]; ax[1]=(bf16)f0[1]; ax[2]=(bf16)f0[2]; ax[3]=(bf16)f0[3];
      ax[4]=(bf16)f1[0]; ax[5]=(bf16)f1[1]; ax[6]=(bf16)f1[2]; ax[7]=(bf16)f1[3];
      if (lowN) {
        a0 = MFMA16(ax, *(const bf16x8*)&sWih[r0*WIHROW + quad*8], a0);
        a1 = MFMA16(ax, *(const bf16x8*)&sWih[r1*WIHROW + quad*8], a1);
        a2 = MFMA16(ax, *(const bf16x8*)&sWih[r2*WIHROW + quad*8], a2);
      } else {
        gi0 = MFMA16(ax, *(const bf16x8*)&sWih[r0*WIHROW + quad*8], gi0);
        gi1 = MFMA16(ax, *(const bf16x8*)&sWih[r1*WIHROW + quad*8], gi1);
      }
    }
    // gh += h @ W_hh^T over K=768 (bf16 exchange buffer)
    {
      const bf16* hrow = g_hbuf + (size_t)par*B_N*H_N + (size_t)gb*H_N;
      #pragma unroll 4
      for (int kt = 0; kt < 24; kt++) {
        const int ko = kt*32 + quad*8;
        bf16x8 af = *(const bf16x8*)(hrow + ko);
        a0 = MFMA16(af, *(const bf16x8*)&sW[r0*WROW + ko], a0);
        a1 = MFMA16(af, *(const bf16x8*)&sW[r1*WROW + ko], a1);
        if (lowN) a2 = MFMA16(af, *(const bf16x8*)&sW[r2*WROW + ko], a2);
      }
    }
    // stage D fragments (disjoint stores per wave)
    {
      const int rb = mi*16 + quad*4;
      const int c0 = lowN ? l16 : 48 + l16;
      const int c1 = lowN ? 16 + l16 : 64 + l16;
      #pragma unroll
      for (int r = 0; r < 4; r++) {
        sGH[rb + r][c0] = a0[r];
        sGH[rb + r][c1] = a1[r];
        if (lowN) sGH[rb + r][32 + l16] = a2[r];
        else { sGIN[rb + r][l16] = gi0[r]; sGIN[rb + r][16 + l16] = gi1[r]; }
      }
    }
    __syncthreads();
    // gates -> h_new slice (PyTorch order r,z,n); f32 master feedback
    {
      bf16* hnxt = g_hbuf + (size_t)(1-par)*B_N*H_N;
      for (int i = tid; i < 768; i += 256) {
        int b = i/24, j = i - b*24;
        float rr = sigmoidf_(sGH[b][j]    + sBih[j]    + sBhh[j]);
        float zz = sigmoidf_(sGH[b][24+j] + sBih[24+j] + sBhh[24+j]);
        float hn = sGH[b][48+j] + sBhh[48+j];
        float in_ = sGIN[b][j]  + sBih[48+j];
        float nn = tanhf_(in_ + rr*hn);
        float hpv = sHm[b][j];
        float hnew = (1.f-zz)*nn + zz*hpv;
        sHm[b][j] = hnew;
        hnxt[(size_t)(g*32+b)*H_N + j0 + j] = (bf16)hnew;
      }
    }
    grp_bar(cptr, nbar*32); nbar++;
    par ^= 1;
    // fused heads for batch bq (full h now available, bf16 copy)
    {
      const bf16* hv = g_hbuf + (size_t)par*B_N*H_N + (size_t)bq*H_N;
      const float* wr = wraww + (size_t)m16*H_N;
      float partial = 0.f;
      #pragma unroll 8
      for (int u = 0; u < 48; u++) {
        int k = s16 + (u<<4);
        partial += (float)hv[k] * wr[k];
      }
      partial += __shfl_xor(partial, 8, 64);
      partial += __shfl_xor(partial, 4, 64);
      partial += __shfl_xor(partial, 2, 64);
      partial += __shfl_xor(partial, 1, 64);
      if (s16 == 0) sHead[m16] = softplusf_(partial + wrawb[m16]);
    }
    __syncthreads();
    if (tid < 16) {
      float wp = sHead[tid];
      float hl = hill[((size_t)bq*T_N + t)*16 + tid];
      if (t == 0) { sWp0[tid] = wp; sHill0[tid] = hl; }
      else {
        size_t o = (size_t)bq*T_N + t;
        float cv = hl*wp;
        hillZ[o*16 + tid] = wp;   // outw: overwrite hillZ (reads of t done)
        hill[o*16 + tid]  = cv;   // outc: overwrite hill with contrib
        float cs = cv;
        cs += __shfl_xor(cs, 8, 64);
        cs += __shfl_xor(cs, 4, 64);
        cs += __shfl_xor(cs, 2, 64);
        cs += __shfl_xor(cs, 1, 64);
        if (tid == 0) outy[o] = cs + g_ctrl[o] + regt + bias0;
        if (t == 1) {  // w_pos[:,0] = 0.5*wp[:,1] + 0.5*wp[:,0]
          float w0 = 0.5f*(wp + sWp0[tid]);
          float c0v = sHill0[tid]*w0;
          size_t o0 = (size_t)bq*T_N;
          hillZ[o0*16 + tid] = w0;
          hill[o0*16 + tid]  = c0v;
          float cs0 = c0v;
          cs0 += __shfl_xor(cs0, 8, 64);
          cs0 += __shfl_xor(cs0, 4, 64);
          cs0 += __shfl_xor(cs0, 2, 64);
          cs0 += __shfl_xor(cs0, 1, 64);
          if (tid == 0) outy[o0] = cs0 + g_ctrl[o0] + regt + bias0;
        }
      }
    }
  }
}

extern "C" void kernel_launch(void* const* d_in, const int* in_sizes, int n_in,
                              void* d_out, int out_size, void* d_ws, size_t ws_size,
                              hipStream_t stream) {
  const float* Xm    = (const float*)d_in[0];
  const float* Xc    = (const float*)d_in[1];
  // d_in[2] = R (int32, unused by the forward value)
  const float* Aw    = (const float*)d_in[3];
  const float* ew1   = (const float*)d_in[4];
  const float* eb1   = (const float*)d_in[5];
  const float* ew2   = (const float*)d_in[6];
  const float* eb2   = (const float*)d_in[7];
  const float* nw    = (const float*)d_in[8];
  const float* nb    = (const float*)d_in[9];
  const float* Wih   = (const float*)d_in[10];
  const float* Whh   = (const float*)d_in[11];
  const float* bih   = (const float*)d_in[12];
  const float* bhh   = (const float*)d_in[13];
  const float* wraww = (const float*)d_in[14];
  const float* wrawb = (const float*)d_in[15];
  const float* alpha = (const float*)d_in[16];
  const float* hilla = (const float*)d_in[17];
  const float* hillg = (const float*)d_in[18];
  const float* cw    = (const float*)d_in[19];
  const float* cb    = (const float*)d_in[20];
  const float* regemb= (const float*)d_in[21];
  const float* bias  = (const float*)d_in[22];
  const float* h0    = (const float*)d_in[23];

  // d_out (f32): y [B*T] | w_pos [B*T*16] | contrib [B*T*16]
  float* outy = (float*)d_out;
  float* outw = outy + 256*512;          // doubles as Z / hillZ scratch
  float* outc = outw + 256*512*16;       // doubles as hill scratch

  k_zero<<<1, 256, 0, stream>>>();
  k_encode<<<512, 256, 0, stream>>>(Xm, Xc, Aw, ew1, eb1, ew2, eb2, nw, nb, cw, cb,
                                    outw);
  k_adstock<<<64, 64, 0, stream>>>(Xm, alpha, hilla, hillg, outw, outc);
  void* args[] = { (void*)&Xc, (void*)&Wih, (void*)&Whh, (void*)&bih, (void*)&bhh,
                   (void*)&wraww, (void*)&wrawb, (void*)&regemb, (void*)&bias, (void*)&h0,
                   (void*)&outw, (void*)&outc, (void*)&outy };
  hipLaunchCooperativeKernel((void*)k_gru, dim3(256), dim3(256), args, 0, stream);
}

// Round 6
// 7340.318 us; speedup vs baseline: 3.2628x; 3.2628x over previous
//
#include <hip/hip_runtime.h>

typedef __bf16 bf16;
typedef bf16 bf16x8 __attribute__((ext_vector_type(8)));
typedef bf16 bf16x4 __attribute__((ext_vector_type(4)));
typedef float f32x4 __attribute__((ext_vector_type(4)));
typedef unsigned long long u64;

#define MFMA16(a,b,c) __builtin_amdgcn_mfma_f32_16x16x32_bf16((a),(b),(c),0,0,0)

#define B_N 256
#define T_N 512
#define H_N 768
#define WROW 776      // 768 + 8 pad: 16B-aligned rows, bank-staggered
#define WIHROW 40     // 32 + 8 pad

// ---- device-global scratch (BSS) ----
__device__ float    g_ctrl[B_N * T_N];          // 512 KB
__device__ bf16     g_hbuf[2 * B_N * H_N];      // 768 KB (bf16 h exchange via MALL atomics)
__device__ float    g_head[2][B_N][16];         // 32 KB  (head-dot accumulators, parity)
__device__ unsigned g_cnt[256];                 // 8 groups x 32 (128B stride)

__device__ __forceinline__ float sigmoidf_(float x){ return 1.f/(1.f+__expf(-x)); }
__device__ __forceinline__ float tanhf_(float x){
  float e = __expf(-2.f*fabsf(x));
  float t = (1.f-e)/(1.f+e);
  return copysignf(t, x);
}
__device__ __forceinline__ float softplusf_(float x){
  return x > 20.f ? x : log1pf(__expf(x));
}

__global__ void k_zero() {
  const int tid = threadIdx.x;
  if (tid < 256) g_cnt[tid] = 0u;
  float* gh = &g_head[0][0][0];
  for (int i = tid; i < 2*B_N*16; i += 256) gh[i] = 0.f;
}

// ---------------- kernel A: causal encoder Z + ctrl term ----------------
__global__ __launch_bounds__(256) void k_encode(
    const float* __restrict__ Xm, const float* __restrict__ Xc,
    const float* __restrict__ Aw,
    const float* __restrict__ ew1, const float* __restrict__ eb1,
    const float* __restrict__ ew2, const float* __restrict__ eb2,
    const float* __restrict__ nw,  const float* __restrict__ nb,
    const float* __restrict__ cw,  const float* __restrict__ cb,
    float* __restrict__ Zout)
{
  __shared__ float sA[16][16], sE1[16][32], sE2[16][16], sNW[16][32];
  __shared__ float sEB1[16], sEB2[16], sNB[16];
  __shared__ float sCW[768][16];
  __shared__ float sCB[768];
  const int tid = threadIdx.x;
  for (int i = tid; i < 256; i += 256) sA[i>>4][i&15] = Aw[i];
  for (int i = tid; i < 512; i += 256) sE1[i>>5][i&31] = ew1[i];
  for (int i = tid; i < 256; i += 256) sE2[i>>4][i&15] = ew2[i];
  for (int i = tid; i < 512; i += 256) sNW[i>>5][i&31] = nw[i];
  if (tid < 16) { sEB1[tid]=eb1[tid]; sEB2[tid]=eb2[tid]; sNB[tid]=nb[tid]; }
  for (int i = tid; i < 768*16; i += 256) sCW[i>>4][i&15] = cw[i];
  for (int i = tid; i < 768; i += 256) sCB[i] = cb[i];
  __syncthreads();
  const int idx = blockIdx.x*256 + tid;           // flat (b*T + t)
  const float* xmp = Xm + (size_t)idx*16;
  const float* xcp = Xc + (size_t)idx*16;
  float xm[16], xc[16];
  #pragma unroll
  for (int j=0;j<4;j++){
    *(f32x4*)&xm[j*4] = *(const f32x4*)(xmp + j*4);
    *(f32x4*)&xc[j*4] = *(const f32x4*)(xcp + j*4);
  }
  float snd[16], rcv[16];
  #pragma unroll
  for (int i=0;i<16;i++){
    float s=0.f, r=0.f;
    #pragma unroll
    for (int j=0;j<16;j++){ s += xm[j]*sA[i][j]; r += xm[j]*sA[j][i]; }
    snd[i]=s; rcv[i]=r;
  }
  float he[16];
  #pragma unroll
  for (int i=0;i<16;i++){
    float a = sEB1[i];
    #pragma unroll
    for (int k=0;k<16;k++) a += snd[k]*sE1[i][k];
    #pragma unroll
    for (int k=0;k<16;k++) a += rcv[k]*sE1[i][16+k];
    he[i] = fmaxf(a, 0.f);
  }
  float he2[16];
  #pragma unroll
  for (int i=0;i<16;i++){
    float a = sEB2[i];
    #pragma unroll
    for (int k=0;k<16;k++) a += he[k]*sE2[i][k];
    he2[i] = fmaxf(a, 0.f);
  }
  float* zp = Zout + (size_t)idx*16;
  #pragma unroll
  for (int m=0;m<16;m++){
    float a = sNB[m];
    #pragma unroll
    for (int k=0;k<16;k++) a += xm[k]*sNW[m][k];
    #pragma unroll
    for (int k=0;k<16;k++) a += he2[k]*sNW[m][16+k];
    zp[m] = fmaxf(a, 0.f);
  }
  float cs = 0.f;
  for (int i=0;i<768;i++){
    float a = sCB[i];
    #pragma unroll
    for (int k=0;k<16;k++) a += xc[k]*sCW[i][k];
    cs += fmaxf(a, 0.f);
  }
  g_ctrl[idx] = cs * 0.3f;
}

// ---------------- kernel B: adstock scan + hill + gru-input ----------------
__global__ __launch_bounds__(64) void k_adstock(
    const float* __restrict__ Xm, const float* __restrict__ alpha,
    const float* __restrict__ hill_a, const float* __restrict__ hill_g,
    float* __restrict__ Zio, float* __restrict__ hill_out)
{
  const int gid = blockIdx.x*64 + threadIdx.x;   // (b, m)
  const int b = gid >> 4, m = gid & 15;
  float a  = fminf(fmaxf(alpha[m],  0.f),  1.f);
  float ha = fminf(fmaxf(hill_a[m], 0.1f), 3.f);
  float hg = fminf(fmaxf(hill_g[m], 0.1f), 2.f);
  float gpow = __powf(hg, ha);
  const float* xp = Xm + (size_t)b*T_N*16 + m;
  float prev = 0.f, cmax = 0.f;
  for (int t=0;t<T_N;t++){ float x = xp[(size_t)t*16]; prev = x + a*prev; cmax = fmaxf(cmax, prev); }
  cmax = fmaxf(cmax, 1e-6f);
  float inv = 1.f/cmax;
  prev = 0.f;
  float* zp  = Zio      + (size_t)b*T_N*16 + m;
  float* hp  = hill_out + (size_t)b*T_N*16 + m;
  for (int t=0;t<T_N;t++){
    float x = xp[(size_t)t*16];
    prev = x + a*prev;
    float xn  = fmaxf(prev*inv, 0.f);
    float num = __powf(xn, ha);
    float h   = num / (num + gpow + 1e-8f);
    float z   = zp[(size_t)t*16];
    hp[(size_t)t*16] = h;
    zp[(size_t)t*16] = h + z;
  }
}

// ---------------- kernel C: persistent GRU + fused heads ----------------
// 8 groups x 32 blocks; block p owns h-dims [p*24,(p+1)*24). Shared state
// (h exchange, head partial dots, barrier counter) moves ONLY through
// relaxed agent-scope atomics (MALL coherence point) — no cache-wide fences.
__device__ __forceinline__ void grp_bar(unsigned* cptr, unsigned target) {
  __syncthreads();   // drains vmcnt per wave -> all prior MALL stores complete
  if (threadIdx.x == 0) {
    __hip_atomic_fetch_add(cptr, 1u, __ATOMIC_RELAXED, __HIP_MEMORY_SCOPE_AGENT);
    while (__hip_atomic_load(cptr, __ATOMIC_RELAXED, __HIP_MEMORY_SCOPE_AGENT) < target)
      __builtin_amdgcn_s_sleep(1);
    __builtin_amdgcn_fence(__ATOMIC_ACQUIRE, "workgroup");  // cheap: no L2 traffic
  }
  __syncthreads();
}

__global__ __launch_bounds__(256, 1) void k_gru(
    const float* __restrict__ Xc,
    const float* __restrict__ Wih, const float* __restrict__ Whh,
    const float* __restrict__ bih, const float* __restrict__ bhh,
    const float* __restrict__ wraww, const float* __restrict__ wrawb,
    const float* __restrict__ regemb, const float* __restrict__ bias,
    const float* __restrict__ h0,
    float* __restrict__ hillZ,       // = outw region (read until step t, then w_pos)
    float* __restrict__ hill,        // = outc region (read hill, overwrite contrib)
    float* __restrict__ outy)
{
  __shared__ __align__(16) bf16 sW[72*WROW];      // 111,744 B
  __shared__ __align__(16) bf16 sWih[72*WIHROW];  //   5,760 B
  __shared__ float sGH[32][84];                   //  10,752 B
  __shared__ float sGIN[32][36];                  //   4,608 B
  __shared__ float sHm[32][24];                   //   3,072 B (f32 master h slice)
  __shared__ float sWr[16][25];                   //   1,600 B (wraww slice, padded)
  __shared__ float sBih[72], sBhh[72];
  __shared__ float sHead[16];
  __shared__ float sScal[2];

  const int g = blockIdx.x & 7, p = blockIdx.x >> 3;
  const int j0 = p*24;
  const int tid = threadIdx.x;
  const int wave = tid >> 6, lane = tid & 63;
  const int quad = lane >> 4, l16 = lane & 15;

  // stage W_hh slice (f32 -> bf16), rows {gate*768 + j0 + j}
  for (int c = tid; c < 72*192; c += 256) {
    int rl = c / 192, off = (c - rl*192)*4;
    int grow = (rl/24)*768 + j0 + (rl%24);
    f32x4 w = *(const f32x4*)&Whh[(size_t)grow*768 + off];
    bf16x4 v; v[0]=(bf16)w[0]; v[1]=(bf16)w[1]; v[2]=(bf16)w[2]; v[3]=(bf16)w[3];
    *(bf16x4*)&sW[rl*WROW + off] = v;
  }
  for (int c = tid; c < 72*8; c += 256) {
    int rl = c >> 3, off = (c & 7)*4;
    int grow = (rl/24)*768 + j0 + (rl%24);
    f32x4 w = *(const f32x4*)&Wih[(size_t)grow*32 + off];
    bf16x4 v; v[0]=(bf16)w[0]; v[1]=(bf16)w[1]; v[2]=(bf16)w[2]; v[3]=(bf16)w[3];
    *(bf16x4*)&sWih[rl*WIHROW + off] = v;
  }
  if (tid < 72) {
    int grow = (tid/24)*768 + j0 + (tid%24);
    sBih[tid] = bih[grow];
    sBhh[tid] = bhh[grow];
  }
  for (int c = tid; c < 16*24; c += 256) {
    int m = c/24, j = c - m*24;
    sWr[m][j] = wraww[(size_t)m*H_N + j0 + j];
  }
  if (wave == 0) {
    float s = 0.f;
    for (int k = lane; k < 768; k += 64) s += regemb[k];  // reg_emb[0]
    #pragma unroll
    for (int off = 32; off; off >>= 1) s += __shfl_xor(s, off, 64);
    if (lane == 0) { sScal[0] = 0.3f*s; sScal[1] = bias[0]; }
  }
  // init h (parity 0): f32 master + bf16 MALL publish (packed pairs)
  {
    unsigned* hb = (unsigned*)g_hbuf;   // parity 0 base
    for (int e = tid; e < 384; e += 256) {
      int b = e/12, j = (e - b*12)*2;
      float f0 = h0[j0+j], f1 = h0[j0+j+1];
      sHm[b][j] = f0; sHm[b][j+1] = f1;
      union { bf16 h[2]; unsigned u; } pk;
      pk.h[0] = (bf16)f0; pk.h[1] = (bf16)f1;
      __hip_atomic_store(&hb[((size_t)(g*32+b)*H_N + j0 + j) >> 1], pk.u,
                         __ATOMIC_RELAXED, __HIP_MEMORY_SCOPE_AGENT);
    }
  }
  unsigned* cptr = g_cnt + g*32;
  unsigned nbar = 1;
  grp_bar(cptr, nbar*32); nbar++;

  const int mi = wave >> 1;
  const bool lowN = !(wave & 1);
  const int batch_l = l16 + mi*16;
  const int gb = g*32 + batch_l;
  const int bq = g*32 + p;
  const float regt = sScal[0], bias0 = sScal[1];
  const int r0 = lowN ? l16        : 48 + l16;
  const int r1 = lowN ? 16 + l16   : min(64 + l16, 71);
  const int r2 = 32 + l16;
  float wp0_r = 0.f, hl0_r = 0.f;   // t=0 head state (lanes tid<16)

  int par = 0;
  for (int t = 0; t < T_N; t++) {
    f32x4 a0 = {0.f,0.f,0.f,0.f}, a1 = a0, a2 = a0, gi0 = a0, gi1 = a0;
    // gi = x @ W_ih^T  (x = [hill+Z | Xc], f32 -> bf16 in-register)
    {
      const float* hz = hillZ + ((size_t)gb*T_N + t)*16;
      const float* xr = Xc    + ((size_t)gb*T_N + t)*16;
      const float* src = (quad < 2) ? (hz + quad*8) : (xr + (quad-2)*8);
      f32x4 f0 = *(const f32x4*)src;
      f32x4 f1 = *(const f32x4*)(src + 4);
      bf16x8 ax;
      ax[0]=(bf16)f0[0]; ax[1]=(bf16)f0[1]; ax[2]=(bf16)f0[2]; ax[3]=(bf16)f0[3];
      ax[4]=(bf16)f1[0]; ax[5]=(bf16)f1[1]; ax[6]=(bf16)f1[2]; ax[7]=(bf16)f1[3];
      if (lowN) {
        a0 = MFMA16(ax, *(const bf16x8*)&sWih[r0*WIHROW + quad*8], a0);
        a1 = MFMA16(ax, *(const bf16x8*)&sWih[r1*WIHROW + quad*8], a1);
        a2 = MFMA16(ax, *(const bf16x8*)&sWih[r2*WIHROW + quad*8], a2);
      } else {
        gi0 = MFMA16(ax, *(const bf16x8*)&sWih[r0*WIHROW + quad*8], gi0);
        gi1 = MFMA16(ax, *(const bf16x8*)&sWih[r1*WIHROW + quad*8], gi1);
      }
    }
    // gh += h @ W_hh^T over K=768; h via MALL atomic loads (8B x2 per frag)
    {
      u64* hrow = (u64*)(g_hbuf + (size_t)par*B_N*H_N + (size_t)gb*H_N);
      #pragma unroll
      for (int kt = 0; kt < 24; kt++) {
        union { u64 q[2]; bf16x8 v; } f;
        f.q[0] = __hip_atomic_load(hrow + kt*8 + quad*2,     __ATOMIC_RELAXED, __HIP_MEMORY_SCOPE_AGENT);
        f.q[1] = __hip_atomic_load(hrow + kt*8 + quad*2 + 1, __ATOMIC_RELAXED, __HIP_MEMORY_SCOPE_AGENT);
        const int ko = kt*32 + quad*8;
        a0 = MFMA16(f.v, *(const bf16x8*)&sW[r0*WROW + ko], a0);
        a1 = MFMA16(f.v, *(const bf16x8*)&sW[r1*WROW + ko], a1);
        if (lowN) a2 = MFMA16(f.v, *(const bf16x8*)&sW[r2*WROW + ko], a2);
      }
    }
    // stage D fragments
    {
      const int rb = mi*16 + quad*4;
      const int c0 = lowN ? l16 : 48 + l16;
      const int c1 = lowN ? 16 + l16 : 64 + l16;
      #pragma unroll
      for (int r = 0; r < 4; r++) {
        sGH[rb + r][c0] = a0[r];
        sGH[rb + r][c1] = a1[r];
        if (lowN) sGH[rb + r][32 + l16] = a2[r];
        else { sGIN[rb + r][l16] = gi0[r]; sGIN[rb + r][16 + l16] = gi1[r]; }
      }
    }
    __syncthreads();
    // gates -> h_new (pairs); f32 master feedback; bf16 MALL publish
    {
      unsigned* hnxt = (unsigned*)(g_hbuf + (size_t)(1-par)*B_N*H_N);
      for (int e = tid; e < 384; e += 256) {
        int b = e/12, j = (e - b*12)*2;
        float hn0, hn1;
        {
          float rr = sigmoidf_(sGH[b][j]    + sBih[j]    + sBhh[j]);
          float zz = sigmoidf_(sGH[b][24+j] + sBih[24+j] + sBhh[24+j]);
          float hh = sGH[b][48+j] + sBhh[48+j];
          float in_ = sGIN[b][j]  + sBih[48+j];
          float nn = tanhf_(in_ + rr*hh);
          hn0 = (1.f-zz)*nn + zz*sHm[b][j];
        }
        {
          int j1 = j+1;
          float rr = sigmoidf_(sGH[b][j1]    + sBih[j1]    + sBhh[j1]);
          float zz = sigmoidf_(sGH[b][24+j1] + sBih[24+j1] + sBhh[24+j1]);
          float hh = sGH[b][48+j1] + sBhh[48+j1];
          float in_ = sGIN[b][j1]  + sBih[48+j1];
          float nn = tanhf_(in_ + rr*hh);
          hn1 = (1.f-zz)*nn + zz*sHm[b][j1];
        }
        sHm[b][j] = hn0; sHm[b][j+1] = hn1;
        union { bf16 h[2]; unsigned u; } pk;
        pk.h[0] = (bf16)hn0; pk.h[1] = (bf16)hn1;
        __hip_atomic_store(&hnxt[((size_t)(g*32+b)*H_N + j0 + j) >> 1], pk.u,
                           __ATOMIC_RELAXED, __HIP_MEMORY_SCOPE_AGENT);
      }
    }
    __syncthreads();
    // partial head dots from f32 slice -> MALL accumulate
    for (int e = tid; e < 512; e += 256) {
      int b = e >> 4, m = e & 15;
      float s = 0.f;
      #pragma unroll
      for (int j = 0; j < 24; j++) s += sHm[b][j]*sWr[m][j];
      __hip_atomic_fetch_add(&g_head[t&1][g*32+b][m], s,
                             __ATOMIC_RELAXED, __HIP_MEMORY_SCOPE_AGENT);
    }
    grp_bar(cptr, nbar*32); nbar++;
    par ^= 1;
    // heads: gather 16 summed dots (4 per wave), softplus, zero for t+2
    if (lane < 4) {
      int m = wave*4 + lane;
      float* hp = &g_head[t&1][bq][m];
      float wd = __hip_atomic_load(hp, __ATOMIC_RELAXED, __HIP_MEMORY_SCOPE_AGENT);
      __hip_atomic_store(hp, 0.f, __ATOMIC_RELAXED, __HIP_MEMORY_SCOPE_AGENT);
      sHead[m] = softplusf_(wd + wrawb[m]);
    }
    __syncthreads();
    if (tid < 16) {
      float wp = sHead[tid];
      float hl = hill[((size_t)bq*T_N + t)*16 + tid];
      if (t == 0) { wp0_r = wp; hl0_r = hl; }
      else {
        size_t o = (size_t)bq*T_N + t;
        float cv = hl*wp;
        hillZ[o*16 + tid] = wp;
        hill[o*16 + tid]  = cv;
        float cs = cv;
        cs += __shfl_xor(cs, 8, 64);
        cs += __shfl_xor(cs, 4, 64);
        cs += __shfl_xor(cs, 2, 64);
        cs += __shfl_xor(cs, 1, 64);
        if (tid == 0) outy[o] = cs + g_ctrl[o] + regt + bias0;
        if (t == 1) {
          float w0 = 0.5f*(wp + wp0_r);
          float c0v = hl0_r*w0;
          size_t o0 = (size_t)bq*T_N;
          hillZ[o0*16 + tid] = w0;
          hill[o0*16 + tid]  = c0v;
          float cs0 = c0v;
          cs0 += __shfl_xor(cs0, 8, 64);
          cs0 += __shfl_xor(cs0, 4, 64);
          cs0 += __shfl_xor(cs0, 2, 64);
          cs0 += __shfl_xor(cs0, 1, 64);
          if (tid == 0) outy[o0] = cs0 + g_ctrl[o0] + regt + bias0;
        }
      }
    }
  }
}

extern "C" void kernel_launch(void* const* d_in, const int* in_sizes, int n_in,
                              void* d_out, int out_size, void* d_ws, size_t ws_size,
                              hipStream_t stream) {
  const float* Xm    = (const float*)d_in[0];
  const float* Xc    = (const float*)d_in[1];
  const float* Aw    = (const float*)d_in[3];
  const float* ew1   = (const float*)d_in[4];
  const float* eb1   = (const float*)d_in[5];
  const float* ew2   = (const float*)d_in[6];
  const float* eb2   = (const float*)d_in[7];
  const float* nw    = (const float*)d_in[8];
  const float* nb    = (const float*)d_in[9];
  const float* Wih   = (const float*)d_in[10];
  const float* Whh   = (const float*)d_in[11];
  const float* bih   = (const float*)d_in[12];
  const float* bhh   = (const float*)d_in[13];
  const float* wraww = (const float*)d_in[14];
  const float* wrawb = (const float*)d_in[15];
  const float* alpha = (const float*)d_in[16];
  const float* hilla = (const float*)d_in[17];
  const float* hillg = (const float*)d_in[18];
  const float* cw    = (const float*)d_in[19];
  const float* cb    = (const float*)d_in[20];
  const float* regemb= (const float*)d_in[21];
  const float* bias  = (const float*)d_in[22];
  const float* h0    = (const float*)d_in[23];

  float* outy = (float*)d_out;
  float* outw = outy + 256*512;          // doubles as Z / hillZ scratch
  float* outc = outw + 256*512*16;       // doubles as hill scratch

  k_zero<<<1, 256, 0, stream>>>();
  k_encode<<<512, 256, 0, stream>>>(Xm, Xc, Aw, ew1, eb1, ew2, eb2, nw, nb, cw, cb,
                                    outw);
  k_adstock<<<64, 64, 0, stream>>>(Xm, alpha, hilla, hillg, outw, outc);
  void* args[] = { (void*)&Xc, (void*)&Wih, (void*)&Whh, (void*)&bih, (void*)&bhh,
                   (void*)&wraww, (void*)&wrawb, (void*)&regemb, (void*)&bias, (void*)&h0,
                   (void*)&outw, (void*)&outc, (void*)&outy };
  (void)hipLaunchCooperativeKernel((void*)k_gru, dim3(256), dim3(256), args, 0, stream);
}

// Round 7
// 6719.781 us; speedup vs baseline: 3.5641x; 1.0923x over previous
//
#include <hip/hip_runtime.h>

typedef __bf16 bf16;
typedef bf16 bf16x8 __attribute__((ext_vector_type(8)));
typedef bf16 bf16x4 __attribute__((ext_vector_type(4)));
typedef float f32x4 __attribute__((ext_vector_type(4)));
typedef unsigned long long u64;

#define MFMA16(a,b,c) __builtin_amdgcn_mfma_f32_16x16x32_bf16((a),(b),(c),0,0,0)

#define B_N 256
#define T_N 512
#define H_N 768
#define WROW 776      // 768 + 8 pad: 16B-aligned rows, bank-staggered
#define WIHROW 40     // 32 + 8 pad

// ---- device-global scratch (BSS) ----
__device__ float    g_ctrl[B_N * T_N];          // 512 KB
__device__ bf16     g_hbuf[2 * B_N * H_N];      // 768 KB (bf16 h exchange via MALL atomics)
__device__ unsigned g_flag[256];                // 8 groups x 32 flags (128B/group)

__device__ __forceinline__ float sigmoidf_(float x){ return 1.f/(1.f+__expf(-x)); }
__device__ __forceinline__ float tanhf_(float x){
  float e = __expf(-2.f*fabsf(x));
  float t = (1.f-e)/(1.f+e);
  return copysignf(t, x);
}
__device__ __forceinline__ float softplusf_(float x){
  return x > 20.f ? x : log1pf(__expf(x));
}

__global__ void k_zero() {
  if (threadIdx.x < 256) g_flag[threadIdx.x] = 0u;
}

// ---------------- kernel A: causal encoder Z + ctrl term ----------------
__global__ __launch_bounds__(256) void k_encode(
    const float* __restrict__ Xm, const float* __restrict__ Xc,
    const float* __restrict__ Aw,
    const float* __restrict__ ew1, const float* __restrict__ eb1,
    const float* __restrict__ ew2, const float* __restrict__ eb2,
    const float* __restrict__ nw,  const float* __restrict__ nb,
    const float* __restrict__ cw,  const float* __restrict__ cb,
    float* __restrict__ Zout)
{
  __shared__ float sA[16][16], sE1[16][32], sE2[16][16], sNW[16][32];
  __shared__ float sEB1[16], sEB2[16], sNB[16];
  __shared__ float sCW[768][16];
  __shared__ float sCB[768];
  const int tid = threadIdx.x;
  for (int i = tid; i < 256; i += 256) sA[i>>4][i&15] = Aw[i];
  for (int i = tid; i < 512; i += 256) sE1[i>>5][i&31] = ew1[i];
  for (int i = tid; i < 256; i += 256) sE2[i>>4][i&15] = ew2[i];
  for (int i = tid; i < 512; i += 256) sNW[i>>5][i&31] = nw[i];
  if (tid < 16) { sEB1[tid]=eb1[tid]; sEB2[tid]=eb2[tid]; sNB[tid]=nb[tid]; }
  for (int i = tid; i < 768*16; i += 256) sCW[i>>4][i&15] = cw[i];
  for (int i = tid; i < 768; i += 256) sCB[i] = cb[i];
  __syncthreads();
  const int idx = blockIdx.x*256 + tid;           // flat (b*T + t)
  const float* xmp = Xm + (size_t)idx*16;
  const float* xcp = Xc + (size_t)idx*16;
  float xm[16], xc[16];
  #pragma unroll
  for (int j=0;j<4;j++){
    *(f32x4*)&xm[j*4] = *(const f32x4*)(xmp + j*4);
    *(f32x4*)&xc[j*4] = *(const f32x4*)(xcp + j*4);
  }
  float snd[16], rcv[16];
  #pragma unroll
  for (int i=0;i<16;i++){
    float s=0.f, r=0.f;
    #pragma unroll
    for (int j=0;j<16;j++){ s += xm[j]*sA[i][j]; r += xm[j]*sA[j][i]; }
    snd[i]=s; rcv[i]=r;
  }
  float he[16];
  #pragma unroll
  for (int i=0;i<16;i++){
    float a = sEB1[i];
    #pragma unroll
    for (int k=0;k<16;k++) a += snd[k]*sE1[i][k];
    #pragma unroll
    for (int k=0;k<16;k++) a += rcv[k]*sE1[i][16+k];
    he[i] = fmaxf(a, 0.f);
  }
  float he2[16];
  #pragma unroll
  for (int i=0;i<16;i++){
    float a = sEB2[i];
    #pragma unroll
    for (int k=0;k<16;k++) a += he[k]*sE2[i][k];
    he2[i] = fmaxf(a, 0.f);
  }
  float* zp = Zout + (size_t)idx*16;
  #pragma unroll
  for (int m=0;m<16;m++){
    float a = sNB[m];
    #pragma unroll
    for (int k=0;k<16;k++) a += xm[k]*sNW[m][k];
    #pragma unroll
    for (int k=0;k<16;k++) a += he2[k]*sNW[m][16+k];
    zp[m] = fmaxf(a, 0.f);
  }
  float cs = 0.f;
  for (int i=0;i<768;i++){
    float a = sCB[i];
    #pragma unroll
    for (int k=0;k<16;k++) a += xc[k]*sCW[i][k];
    cs += fmaxf(a, 0.f);
  }
  g_ctrl[idx] = cs * 0.3f;
}

// ---------------- kernel B: adstock scan + hill + gru-input ----------------
__global__ __launch_bounds__(64) void k_adstock(
    const float* __restrict__ Xm, const float* __restrict__ alpha,
    const float* __restrict__ hill_a, const float* __restrict__ hill_g,
    float* __restrict__ Zio, float* __restrict__ hill_out)
{
  const int gid = blockIdx.x*64 + threadIdx.x;   // (b, m)
  const int b = gid >> 4, m = gid & 15;
  float a  = fminf(fmaxf(alpha[m],  0.f),  1.f);
  float ha = fminf(fmaxf(hill_a[m], 0.1f), 3.f);
  float hg = fminf(fmaxf(hill_g[m], 0.1f), 2.f);
  float gpow = __powf(hg, ha);
  const float* xp = Xm + (size_t)b*T_N*16 + m;
  float prev = 0.f, cmax = 0.f;
  for (int t=0;t<T_N;t++){ float x = xp[(size_t)t*16]; prev = x + a*prev; cmax = fmaxf(cmax, prev); }
  cmax = fmaxf(cmax, 1e-6f);
  float inv = 1.f/cmax;
  prev = 0.f;
  float* zp  = Zio      + (size_t)b*T_N*16 + m;
  float* hp  = hill_out + (size_t)b*T_N*16 + m;
  for (int t=0;t<T_N;t++){
    float x = xp[(size_t)t*16];
    prev = x + a*prev;
    float xn  = fmaxf(prev*inv, 0.f);
    float num = __powf(xn, ha);
    float h   = num / (num + gpow + 1e-8f);
    float z   = zp[(size_t)t*16];
    hp[(size_t)t*16] = h;
    zp[(size_t)t*16] = h + z;
  }
}

// ---------------- kernel C: persistent GRU + fused heads ----------------
// 8 groups x 32 blocks; block p owns h-dims [p*24,(p+1)*24). h exchange via
// relaxed agent-scope atomics (MALL). Heads computed as extra MFMA columns
// (wraww rows 72..87 of the B-tile) from the K-loop's A-fragments, one step
// deferred. Barrier = distributed per-block flags (no contended RMW).
__device__ __forceinline__ void grp_bar(unsigned* flags, int p, unsigned val,
                                        int lane, int wave) {
  __syncthreads();   // drains vmcnt per wave -> all prior MALL stores complete
  if (wave == 0) {
    if (lane == 0)
      __hip_atomic_store(&flags[p], val, __ATOMIC_RELAXED, __HIP_MEMORY_SCOPE_AGENT);
    const int idx = lane & 31;
    for (;;) {
      unsigned v = __hip_atomic_load(&flags[idx], __ATOMIC_RELAXED, __HIP_MEMORY_SCOPE_AGENT);
      if (__ballot(v >= val) == ~0ull) break;
      __builtin_amdgcn_s_sleep(1);
    }
    __builtin_amdgcn_fence(__ATOMIC_ACQUIRE, "workgroup");
  }
  __syncthreads();
}

__global__ __launch_bounds__(256, 1) void k_gru(
    const float* __restrict__ Xc,
    const float* __restrict__ Wih, const float* __restrict__ Whh,
    const float* __restrict__ bih, const float* __restrict__ bhh,
    const float* __restrict__ wraww, const float* __restrict__ wrawb,
    const float* __restrict__ regemb, const float* __restrict__ bias,
    const float* __restrict__ h0,
    float* __restrict__ hillZ,       // = outw region (read until step t, then w_pos)
    float* __restrict__ hill,        // = outc region (read hill, overwrite contrib)
    float* __restrict__ outy)
{
  __shared__ __align__(16) bf16 sW[88*WROW];      // 136,576 B (72 Whh rows + 16 wraww)
  __shared__ __align__(16) bf16 sWih[72*WIHROW];  //   5,760 B
  __shared__ float sGH[32][84];                   //  10,752 B
  __shared__ float sGIN[32][36];                  //   4,608 B
  __shared__ float sHm[32][24];                   //   3,072 B (f32 master h slice)
  __shared__ float sHD[32][17];                   //   2,176 B (head MFMA D tile)
  __shared__ float sBih[72], sBhh[72];            //     576 B
  __shared__ float sWrb[16];                      //      64 B
  __shared__ float sScal[2];                      //       8 B   -> 163,592 total

  const int g = blockIdx.x & 7, p = blockIdx.x >> 3;
  const int j0 = p*24;
  const int tid = threadIdx.x;
  const int wave = tid >> 6, lane = tid & 63;
  const int quad = lane >> 4, l16 = lane & 15;

  // stage B-tile: rows 0..71 = Whh slice (f32->bf16), rows 72..87 = wraww
  for (int c = tid; c < 88*192; c += 256) {
    int rl = c / 192, off = (c - rl*192)*4;
    const float* src = (rl < 72)
        ? &Whh[(size_t)((rl/24)*768 + j0 + (rl%24))*768 + off]
        : &wraww[(size_t)(rl-72)*768 + off];
    f32x4 w = *(const f32x4*)src;
    bf16x4 v; v[0]=(bf16)w[0]; v[1]=(bf16)w[1]; v[2]=(bf16)w[2]; v[3]=(bf16)w[3];
    *(bf16x4*)&sW[rl*WROW + off] = v;
  }
  for (int c = tid; c < 72*8; c += 256) {
    int rl = c >> 3, off = (c & 7)*4;
    int grow = (rl/24)*768 + j0 + (rl%24);
    f32x4 w = *(const f32x4*)&Wih[(size_t)grow*32 + off];
    bf16x4 v; v[0]=(bf16)w[0]; v[1]=(bf16)w[1]; v[2]=(bf16)w[2]; v[3]=(bf16)w[3];
    *(bf16x4*)&sWih[rl*WIHROW + off] = v;
  }
  if (tid < 72) {
    int grow = (tid/24)*768 + j0 + (tid%24);
    sBih[tid] = bih[grow];
    sBhh[tid] = bhh[grow];
  }
  if (tid >= 128 && tid < 144) sWrb[tid-128] = wrawb[tid-128];
  if (wave == 0) {
    float s = 0.f;
    for (int k = lane; k < 768; k += 64) s += regemb[k];  // reg_emb[0]
    #pragma unroll
    for (int off = 32; off; off >>= 1) s += __shfl_xor(s, off, 64);
    if (lane == 0) { sScal[0] = 0.3f*s; sScal[1] = bias[0]; }
  }
  // init h (parity 0): f32 master + bf16 MALL publish (packed pairs)
  {
    unsigned* hb = (unsigned*)g_hbuf;
    for (int e = tid; e < 384; e += 256) {
      int b = e/12, j = (e - b*12)*2;
      float f0 = h0[j0+j], f1 = h0[j0+j+1];
      sHm[b][j] = f0; sHm[b][j+1] = f1;
      union { bf16 h[2]; unsigned u; } pk;
      pk.h[0] = (bf16)f0; pk.h[1] = (bf16)f1;
      __hip_atomic_store(&hb[((size_t)(g*32+b)*H_N + j0 + j) >> 1], pk.u,
                         __ATOMIC_RELAXED, __HIP_MEMORY_SCOPE_AGENT);
    }
  }
  unsigned* flags = g_flag + g*32;
  grp_bar(flags, p, 1u, lane, wave);

  const int mi = wave >> 1;
  const bool lowN = !(wave & 1);
  const int batch_l = l16 + mi*16;
  const int gb = g*32 + batch_l;
  const int bq = g*32 + p;
  const float regt = sScal[0], bias0 = sScal[1];
  const int r0 = lowN ? l16        : 48 + l16;
  const int r1 = lowN ? 16 + l16   : min(64 + l16, 71);
  const int r2 = 32 + l16;                 // lowN only
  const int rh = 72 + l16;                 // head rows (hiN only)
  float wp0_r = 0.f, hl0_r = 0.f;          // t=0 head state (lanes tid<16)

  int par = 0;
  for (int t = 0; t < T_N; t++) {
    f32x4 a0 = {0.f,0.f,0.f,0.f}, a1 = a0, a2 = a0, gi0 = a0, gi1 = a0, hd = a0;
    // gi = x @ W_ih^T  (x = [hill+Z | Xc], f32 -> bf16 in-register)
    {
      const float* hz = hillZ + ((size_t)gb*T_N + t)*16;
      const float* xr = Xc    + ((size_t)gb*T_N + t)*16;
      const float* src = (quad < 2) ? (hz + quad*8) : (xr + (quad-2)*8);
      f32x4 f0 = *(const f32x4*)src;
      f32x4 f1 = *(const f32x4*)(src + 4);
      bf16x8 ax;
      ax[0]=(bf16)f0[0]; ax[1]=(bf16)f0[1]; ax[2]=(bf16)f0[2]; ax[3]=(bf16)f0[3];
      ax[4]=(bf16)f1[0]; ax[5]=(bf16)f1[1]; ax[6]=(bf16)f1[2]; ax[7]=(bf16)f1[3];
      if (lowN) {
        a0 = MFMA16(ax, *(const bf16x8*)&sWih[r0*WIHROW + quad*8], a0);
        a1 = MFMA16(ax, *(const bf16x8*)&sWih[r1*WIHROW + quad*8], a1);
        a2 = MFMA16(ax, *(const bf16x8*)&sWih[r2*WIHROW + quad*8], a2);
      } else {
        gi0 = MFMA16(ax, *(const bf16x8*)&sWih[r0*WIHROW + quad*8], gi0);
        gi1 = MFMA16(ax, *(const bf16x8*)&sWih[r1*WIHROW + quad*8], gi1);
      }
    }
    // batched MALL loads of h fragments (A = h_seq[t-1]), then MFMA
    {
      u64* hrow = (u64*)(g_hbuf + (size_t)par*B_N*H_N + (size_t)gb*H_N);
      bf16x8 hf[24];
      #pragma unroll
      for (int kt = 0; kt < 24; kt++) {
        union { u64 q[2]; bf16x8 v; } f;
        f.q[0] = __hip_atomic_load(hrow + kt*8 + quad*2,     __ATOMIC_RELAXED, __HIP_MEMORY_SCOPE_AGENT);
        f.q[1] = __hip_atomic_load(hrow + kt*8 + quad*2 + 1, __ATOMIC_RELAXED, __HIP_MEMORY_SCOPE_AGENT);
        hf[kt] = f.v;
      }
      #pragma unroll
      for (int kt = 0; kt < 24; kt++) {
        const int ko = kt*32 + quad*8;
        a0 = MFMA16(hf[kt], *(const bf16x8*)&sW[r0*WROW + ko], a0);
        a1 = MFMA16(hf[kt], *(const bf16x8*)&sW[r1*WROW + ko], a1);
        if (lowN) a2 = MFMA16(hf[kt], *(const bf16x8*)&sW[r2*WROW + ko], a2);
        else      hd = MFMA16(hf[kt], *(const bf16x8*)&sW[rh*WROW + ko], hd);
      }
    }
    // stage D fragments
    {
      const int rb = mi*16 + quad*4;
      const int c0 = lowN ? l16 : 48 + l16;
      const int c1 = lowN ? 16 + l16 : 64 + l16;
      #pragma unroll
      for (int r = 0; r < 4; r++) {
        sGH[rb + r][c0] = a0[r];
        sGH[rb + r][c1] = a1[r];
        if (lowN) sGH[rb + r][32 + l16] = a2[r];
        else { sGIN[rb + r][l16] = gi0[r]; sGIN[rb + r][16 + l16] = gi1[r];
               sHD[rb + r][l16] = hd[r]; }
      }
    }
    __syncthreads();
    // epilogue for output tt = t-1 (head of h_seq[t-1] staged in sHD)
    if (t > 0 && tid < 16) {
      const int tt = t - 1;
      float wp = softplusf_(sHD[p][tid] + sWrb[tid]);
      float hl = hill[((size_t)bq*T_N + tt)*16 + tid];
      if (tt == 0) { wp0_r = wp; hl0_r = hl; }
      else {
        size_t o = (size_t)bq*T_N + tt;
        float cv = hl*wp;
        hillZ[o*16 + tid] = wp;
        hill[o*16 + tid]  = cv;
        float cs = cv;
        cs += __shfl_xor(cs, 8, 64);
        cs += __shfl_xor(cs, 4, 64);
        cs += __shfl_xor(cs, 2, 64);
        cs += __shfl_xor(cs, 1, 64);
        if (tid == 0) outy[o] = cs + g_ctrl[o] + regt + bias0;
        if (tt == 1) {
          float w0 = 0.5f*(wp + wp0_r);
          float c0v = hl0_r*w0;
          size_t o0 = (size_t)bq*T_N;
          hillZ[o0*16 + tid] = w0;
          hill[o0*16 + tid]  = c0v;
          float cs0 = c0v;
          cs0 += __shfl_xor(cs0, 8, 64);
          cs0 += __shfl_xor(cs0, 4, 64);
          cs0 += __shfl_xor(cs0, 2, 64);
          cs0 += __shfl_xor(cs0, 1, 64);
          if (tid == 0) outy[o0] = cs0 + g_ctrl[o0] + regt + bias0;
        }
      }
    }
    // gates -> h_new (pairs); f32 master feedback; bf16 MALL publish
    {
      unsigned* hnxt = (unsigned*)(g_hbuf + (size_t)(1-par)*B_N*H_N);
      for (int e = tid; e < 384; e += 256) {
        int b = e/12, j = (e - b*12)*2;
        float hn0, hn1;
        {
          float rr = sigmoidf_(sGH[b][j]    + sBih[j]    + sBhh[j]);
          float zz = sigmoidf_(sGH[b][24+j] + sBih[24+j] + sBhh[24+j]);
          float hh = sGH[b][48+j] + sBhh[48+j];
          float in_ = sGIN[b][j]  + sBih[48+j];
          float nn = tanhf_(in_ + rr*hh);
          hn0 = (1.f-zz)*nn + zz*sHm[b][j];
        }
        {
          int j1 = j+1;
          float rr = sigmoidf_(sGH[b][j1]    + sBih[j1]    + sBhh[j1]);
          float zz = sigmoidf_(sGH[b][24+j1] + sBih[24+j1] + sBhh[24+j1]);
          float hh = sGH[b][48+j1] + sBhh[48+j1];
          float in_ = sGIN[b][j1]  + sBih[48+j1];
          float nn = tanhf_(in_ + rr*hh);
          hn1 = (1.f-zz)*nn + zz*sHm[b][j1];
        }
        sHm[b][j] = hn0; sHm[b][j+1] = hn1;
        union { bf16 h[2]; unsigned u; } pk;
        pk.h[0] = (bf16)hn0; pk.h[1] = (bf16)hn1;
        __hip_atomic_store(&hnxt[((size_t)(g*32+b)*H_N + j0 + j) >> 1], pk.u,
                           __ATOMIC_RELAXED, __HIP_MEMORY_SCOPE_AGENT);
      }
    }
    grp_bar(flags, p, (unsigned)(t + 2), lane, wave);
    par ^= 1;
  }
  // tail: head for tt = T-1 from h_seq[T-1] (all publishes barrier-synced)
  if (wave & 1) {
    u64* hrow = (u64*)(g_hbuf + (size_t)par*B_N*H_N + (size_t)gb*H_N);
    f32x4 hd = {0.f,0.f,0.f,0.f};
    bf16x8 hf[24];
    #pragma unroll
    for (int kt = 0; kt < 24; kt++) {
      union { u64 q[2]; bf16x8 v; } f;
      f.q[0] = __hip_atomic_load(hrow + kt*8 + quad*2,     __ATOMIC_RELAXED, __HIP_MEMORY_SCOPE_AGENT);
      f.q[1] = __hip_atomic_load(hrow + kt*8 + quad*2 + 1, __ATOMIC_RELAXED, __HIP_MEMORY_SCOPE_AGENT);
      hf[kt] = f.v;
    }
    #pragma unroll
    for (int kt = 0; kt < 24; kt++) {
      const int ko = kt*32 + quad*8;
      hd = MFMA16(hf[kt], *(const bf16x8*)&sW[rh*WROW + ko], hd);
    }
    const int rb = mi*16 + quad*4;
    #pragma unroll
    for (int r = 0; r < 4; r++) sHD[rb + r][l16] = hd[r];
  }
  __syncthreads();
  if (tid < 16) {
    const int tt = T_N - 1;
    float wp = softplusf_(sHD[p][tid] + sWrb[tid]);
    float hl = hill[((size_t)bq*T_N + tt)*16 + tid];
    size_t o = (size_t)bq*T_N + tt;
    float cv = hl*wp;
    hillZ[o*16 + tid] = wp;
    hill[o*16 + tid]  = cv;
    float cs = cv;
    cs += __shfl_xor(cs, 8, 64);
    cs += __shfl_xor(cs, 4, 64);
    cs += __shfl_xor(cs, 2, 64);
    cs += __shfl_xor(cs, 1, 64);
    if (tid == 0) outy[o] = cs + g_ctrl[o] + regt + bias0;
  }
}

extern "C" void kernel_launch(void* const* d_in, const int* in_sizes, int n_in,
                              void* d_out, int out_size, void* d_ws, size_t ws_size,
                              hipStream_t stream) {
  const float* Xm    = (const float*)d_in[0];
  const float* Xc    = (const float*)d_in[1];
  const float* Aw    = (const float*)d_in[3];
  const float* ew1   = (const float*)d_in[4];
  const float* eb1   = (const float*)d_in[5];
  const float* ew2   = (const float*)d_in[6];
  const float* eb2   = (const float*)d_in[7];
  const float* nw    = (const float*)d_in[8];
  const float* nb    = (const float*)d_in[9];
  const float* Wih   = (const float*)d_in[10];
  const float* Whh   = (const float*)d_in[11];
  const float* bih   = (const float*)d_in[12];
  const float* bhh   = (const float*)d_in[13];
  const float* wraww = (const float*)d_in[14];
  const float* wrawb = (const float*)d_in[15];
  const float* alpha = (const float*)d_in[16];
  const float* hilla = (const float*)d_in[17];
  const float* hillg = (const float*)d_in[18];
  const float* cw    = (const float*)d_in[19];
  const float* cb    = (const float*)d_in[20];
  const float* regemb= (const float*)d_in[21];
  const float* bias  = (const float*)d_in[22];
  const float* h0    = (const float*)d_in[23];

  float* outy = (float*)d_out;
  float* outw = outy + 256*512;          // doubles as Z / hillZ scratch
  float* outc = outw + 256*512*16;       // doubles as hill scratch

  k_zero<<<1, 256, 0, stream>>>();
  k_encode<<<512, 256, 0, stream>>>(Xm, Xc, Aw, ew1, eb1, ew2, eb2, nw, nb, cw, cb,
                                    outw);
  k_adstock<<<64, 64, 0, stream>>>(Xm, alpha, hilla, hillg, outw, outc);
  void* args[] = { (void*)&Xc, (void*)&Wih, (void*)&Whh, (void*)&bih, (void*)&bhh,
                   (void*)&wraww, (void*)&wrawb, (void*)&regemb, (void*)&bias, (void*)&h0,
                   (void*)&outw, (void*)&outc, (void*)&outy };
  (void)hipLaunchCooperativeKernel((void*)k_gru, dim3(256), dim3(256), args, 0, stream);
}